// Round 1
// baseline (133.229 us; speedup 1.0000x reference)
//
#include <hip/hip_runtime.h>
#include <math.h>

#define BB 64
#define D0 768
#define D2 2304
#define HH 512
#define NG0 8192
#define NC0 8
#define NG1 65536
#define NCH1 11
#define TK1 32
#define TK2 64
#define NC1 (TK1*NC0)   /* 256 */
#define NC2 (TK2*NCH1)  /* 704 */

__device__ __forceinline__ float sigmoidf_(float x){ return 1.0f/(1.0f+expf(-x)); }
__device__ __forceinline__ float geluf_(float x){ return 0.5f*x*(1.0f+erff(x*0.70710678118654752f)); }

// ---------------- Kernel 1: h partial GEMMs (split-k), 160 blocks -----------
// m0: feat5@W0 (Dm=768, 4 splits)  blocks 0..31   tile=bid>>2 split=bid&3
// m1: feat8@W1 (Dm=768, 4 splits)  blocks 32..63
// m2: featcat@W2 (Dm=2304, 12 splits) blocks 64..159
__global__ __launch_bounds__(256) void gemm_h_kernel(
    const float* __restrict__ feat5, const float* __restrict__ feat8,
    const float* __restrict__ featcat,
    const float* __restrict__ W0, const float* __restrict__ W1,
    const float* __restrict__ W2, float* __restrict__ P)
{
  int bid = blockIdx.x;
  const float* X; const float* W; int Dm, split, tile; float* Pb;
  if (bid < 32)      { X=feat5;   W=W0; Dm=D0; tile=bid>>2;        split=bid&3;        Pb=P + (size_t)split*(BB*HH); }
  else if (bid < 64) { int l=bid-32; X=feat8; W=W1; Dm=D0; tile=l>>2; split=l&3;       Pb=P + (size_t)(4+split)*(BB*HH); }
  else               { int l=bid-64; X=featcat; W=W2; Dm=D2; tile=l/12; split=l%12;    Pb=P + (size_t)(8+split)*(BB*HH); }
  int k0 = split*192;
  int jt = tile*64;
  __shared__ __align__(16) float At[32][68];   // [k][b]
  __shared__ __align__(16) float Bt[32][68];   // [k][j]
  int tid = threadIdx.x;
  int ti = tid >> 4, tj = tid & 15;
  float acc[4][4] = {};
  for (int ks = 0; ks < 192; ks += 32) {
    #pragma unroll
    for (int it = 0; it < 2; ++it) {             // A: 64b x 32k
      int q = tid + it*256;
      int b = q & 63, kq = q >> 6;
      float4 v = *(const float4*)(X + (size_t)b*Dm + k0 + ks + kq*4);
      At[kq*4+0][b]=v.x; At[kq*4+1][b]=v.y; At[kq*4+2][b]=v.z; At[kq*4+3][b]=v.w;
    }
    #pragma unroll
    for (int it = 0; it < 2; ++it) {             // B: 32k x 64j (W is [k][j], j contig)
      int q = tid + it*256;
      int j4 = q & 15, kk = q >> 4;
      float4 v = *(const float4*)(W + (size_t)(k0+ks+kk)*HH + jt + j4*4);
      *(float4*)&Bt[kk][j4*4] = v;
    }
    __syncthreads();
    #pragma unroll
    for (int k = 0; k < 32; ++k) {
      float4 a = *(const float4*)&At[k][ti*4];
      float4 b = *(const float4*)&Bt[k][tj*4];
      float av[4] = {a.x,a.y,a.z,a.w};
      float bv[4] = {b.x,b.y,b.z,b.w};
      #pragma unroll
      for (int r=0;r<4;++r)
        #pragma unroll
        for (int c=0;c<4;++c) acc[r][c] += av[r]*bv[c];
    }
    __syncthreads();
  }
  #pragma unroll
  for (int r=0;r<4;++r)
    #pragma unroll
    for (int c=0;c<4;++c) {
      int b = ti*4+r; int j = jt + tj*4 + c;
      Pb[(size_t)b*HH + j] = acc[r][c];
    }
}

// ---------------- Kernel 2: reduce splits + bias + GELU ---------------------
__global__ __launch_bounds__(256) void reduce_gelu_kernel(
    const float* __restrict__ P, const float* __restrict__ b0,
    const float* __restrict__ b1, const float* __restrict__ b2,
    float* __restrict__ h)
{
  int idx = blockIdx.x*256 + threadIdx.x;   // 0..98303
  int m = idx >> 15;
  int r = idx & 32767;
  int j = r & 511;
  const float* Pb; int S; const float* bias;
  if (m==0)      { Pb=P;            S=4;  bias=b0; }
  else if (m==1) { Pb=P+4*(BB*HH);  S=4;  bias=b1; }
  else           { Pb=P+8*(BB*HH);  S=12; bias=b2; }
  float s = 0.0f;
  for (int t=0;t<S;++t) s += Pb[(size_t)t*(BB*HH) + r];
  s += bias[j];
  h[(size_t)m*(BB*HH) + r] = geluf_(s);
}

// ---------------- Kernel 3: level0 p0 = sigmoid(h0 @ E0^T) ------------------
// 256 blocks: btile = bid&1 (32 rows), gt = bid>>1 (64 g cols)
__global__ __launch_bounds__(256) void level0_kernel(
    const float* __restrict__ h0, const float* __restrict__ E0,
    float* __restrict__ p0out)
{
  int bid = blockIdx.x;
  int btile = bid & 1;
  int gt = bid >> 1;
  __shared__ __align__(16) float At[32][36];   // [k][b]  (32 b)
  __shared__ __align__(16) float Bt[32][68];   // [k][g]
  int tid = threadIdx.x;
  int ti = tid >> 4, tj = tid & 15;
  float acc[2][4] = {};
  for (int ks = 0; ks < HH; ks += 32) {
    {
      int q = tid; int b = q & 31, kq = q >> 5;
      float4 v = *(const float4*)(h0 + (size_t)(btile*32 + b)*HH + ks + kq*4);
      At[kq*4+0][b]=v.x; At[kq*4+1][b]=v.y; At[kq*4+2][b]=v.z; At[kq*4+3][b]=v.w;
    }
    #pragma unroll
    for (int it=0; it<2; ++it) {
      int q = tid + it*256; int g = q & 63, kq = q >> 6;
      float4 v = *(const float4*)(E0 + (size_t)(gt*64+g)*HH + ks + kq*4);
      Bt[kq*4+0][g]=v.x; Bt[kq*4+1][g]=v.y; Bt[kq*4+2][g]=v.z; Bt[kq*4+3][g]=v.w;
    }
    __syncthreads();
    #pragma unroll
    for (int k=0;k<32;++k) {
      float2 a = *(const float2*)&At[k][ti*2];
      float4 b = *(const float4*)&Bt[k][tj*4];
      float av[2] = {a.x,a.y};
      float bv[4] = {b.x,b.y,b.z,b.w};
      #pragma unroll
      for (int r=0;r<2;++r)
        #pragma unroll
        for (int c=0;c<4;++c) acc[r][c] += av[r]*bv[c];
    }
    __syncthreads();
  }
  #pragma unroll
  for (int r=0;r<2;++r)
    #pragma unroll
    for (int c=0;c<4;++c) {
      int b = btile*32 + ti*2 + r;
      int g = gt*64 + tj*4 + c;
      p0out[(size_t)b*NG0 + g] = sigmoidf_(acc[r][c]);
    }
}

// ---------------- Kernel 4: top-32 of p0 row + expand cands1 ----------------
__global__ __launch_bounds__(256) void topk1_kernel(
    const float* __restrict__ p0, const int* __restrict__ g0,
    int* __restrict__ cands1_i, float* __restrict__ gsc1,
    float* __restrict__ out_c1)
{
  int b = blockIdx.x, tid = threadIdx.x;
  int lane = tid & 63, wid = tid >> 6;
  const float* row = p0 + (size_t)b*NG0;
  unsigned long long keys[32];
  #pragma unroll
  for (int j=0;j<32;++j) {
    int i = tid + j*256;
    float v = row[i];
    keys[j] = ((unsigned long long)__float_as_uint(v) << 32) |
              (unsigned long long)(0xFFFFFFFFu - (unsigned)i);
  }
  __shared__ unsigned long long wmax[4];
  __shared__ float s_sc[TK1];
  __shared__ int   s_idx[TK1];
  for (int t=0;t<TK1;++t) {
    unsigned long long lm = 0ull;
    #pragma unroll
    for (int j=0;j<32;++j) lm = keys[j] > lm ? keys[j] : lm;
    #pragma unroll
    for (int off=1; off<64; off<<=1) {
      unsigned long long o = __shfl_xor(lm, off);
      lm = o > lm ? o : lm;
    }
    if (lane==0) wmax[wid]=lm;
    __syncthreads();
    unsigned long long w = wmax[0];
    #pragma unroll
    for (int u=1;u<4;++u) w = wmax[u] > w ? wmax[u] : w;
    #pragma unroll
    for (int j=0;j<32;++j) if (keys[j]==w) keys[j]=0ull;
    if (tid==0) {
      unsigned lo = (unsigned)(w & 0xFFFFFFFFull);
      s_idx[t] = (int)(0xFFFFFFFFu - lo);
      s_sc[t]  = __uint_as_float((unsigned)(w>>32));
    }
    __syncthreads();
  }
  if (tid < NC1) {
    int k = tid >> 3, c = tid & 7;
    int cand = g0[(size_t)s_idx[k]*NC0 + c];
    cands1_i[(size_t)b*NC1+tid] = cand;
    gsc1[(size_t)b*NC1+tid] = s_sc[k];
    out_c1[(size_t)b*NC1+tid] = (float)cand;
  }
}

// ---------------- Kernel 5: level1 gather-GEMV over E1 ----------------------
// grid (64, 16): block handles 16 cands; each wave 4 cands
__global__ __launch_bounds__(256) void level1_kernel(
    const float* __restrict__ h1, const int* __restrict__ cands1_i,
    const float* __restrict__ gsc1, const float* __restrict__ E1,
    float* __restrict__ p1out, float* __restrict__ w1out)
{
  int b = blockIdx.x; int tid = threadIdx.x;
  int lane = tid & 63, wid = tid >> 6;
  const float4* h4 = (const float4*)(h1 + (size_t)b*HH);
  float4 ha = h4[lane*2], hb = h4[lane*2+1];
  #pragma unroll
  for (int q=0;q<4;++q) {
    int c = blockIdx.y*16 + wid*4 + q;
    int cand = cands1_i[(size_t)b*NC1 + c];
    const float4* e4 = (const float4*)(E1 + (size_t)cand*HH);
    float4 ea = e4[lane*2], eb = e4[lane*2+1];
    float s = ha.x*ea.x + ha.y*ea.y + ha.z*ea.z + ha.w*ea.w
            + hb.x*eb.x + hb.y*eb.y + hb.z*eb.z + hb.w*eb.w;
    #pragma unroll
    for (int off=1; off<64; off<<=1) s += __shfl_xor(s, off);
    if (lane==0) {
      float p = sigmoidf_(s);
      p1out[(size_t)b*NC1+c] = p;
      w1out[(size_t)b*NC1+c] = p * gsc1[(size_t)b*NC1+c];
    }
  }
}

// ---------------- Kernel 6: top-64 of p1 row + expand cands2 ----------------
__global__ __launch_bounds__(256) void topk2_kernel(
    const float* __restrict__ p1, const int* __restrict__ cands1_i,
    const int* __restrict__ g1,
    int* __restrict__ cands2_i, float* __restrict__ gsc2,
    float* __restrict__ out_c2)
{
  int b = blockIdx.x, tid = threadIdx.x;
  int lane = tid & 63, wid = tid >> 6;
  float v = p1[(size_t)b*NC1 + tid];
  unsigned long long key = ((unsigned long long)__float_as_uint(v) << 32) |
                           (unsigned long long)(0xFFFFFFFFu - (unsigned)tid);
  __shared__ unsigned long long wmax[4];
  __shared__ float s_sc[TK2];
  __shared__ int   s_idx[TK2];
  for (int t=0;t<TK2;++t) {
    unsigned long long lm = key;
    #pragma unroll
    for (int off=1; off<64; off<<=1) {
      unsigned long long o = __shfl_xor(lm, off);
      lm = o > lm ? o : lm;
    }
    if (lane==0) wmax[wid]=lm;
    __syncthreads();
    unsigned long long w = wmax[0];
    #pragma unroll
    for (int u=1;u<4;++u) w = wmax[u] > w ? wmax[u] : w;
    if (key==w) key=0ull;
    if (tid==0) {
      unsigned lo = (unsigned)(w & 0xFFFFFFFFull);
      s_idx[t] = (int)(0xFFFFFFFFu - lo);
      s_sc[t]  = __uint_as_float((unsigned)(w>>32));
    }
    __syncthreads();
  }
  for (int e=tid; e<NC2; e+=256) {
    int k = e/NCH1, c = e - k*NCH1;
    int meta = cands1_i[(size_t)b*NC1 + s_idx[k]];
    int cand = g1[(size_t)meta*NCH1 + c];
    cands2_i[(size_t)b*NC2+e] = cand;
    gsc2[(size_t)b*NC2+e] = s_sc[k];
    out_c2[(size_t)b*NC2+e] = (float)cand;
  }
}

// ---------------- Kernel 7: level2 gather-GEMV over E2 ----------------------
// grid (64, 44): block 16 cands; wave 4 cands
__global__ __launch_bounds__(256) void level2_kernel(
    const float* __restrict__ h2, const int* __restrict__ cands2_i,
    const float* __restrict__ gsc2, const float* __restrict__ E2,
    float* __restrict__ p2out, float* __restrict__ w2out)
{
  int b = blockIdx.x; int tid = threadIdx.x;
  int lane = tid & 63, wid = tid >> 6;
  const float4* h4 = (const float4*)(h2 + (size_t)b*HH);
  float4 ha = h4[lane*2], hb = h4[lane*2+1];
  #pragma unroll
  for (int q=0;q<4;++q) {
    int c = blockIdx.y*16 + wid*4 + q;
    int cand = cands2_i[(size_t)b*NC2 + c];
    const float4* e4 = (const float4*)(E2 + (size_t)cand*HH);
    float4 ea = e4[lane*2], eb = e4[lane*2+1];
    float s = ha.x*ea.x + ha.y*ea.y + ha.z*ea.z + ha.w*ea.w
            + hb.x*eb.x + hb.y*eb.y + hb.z*eb.z + hb.w*eb.w;
    #pragma unroll
    for (int off=1; off<64; off<<=1) s += __shfl_xor(s, off);
    if (lane==0) {
      float p = (s == 0.0f) ? 0.0f : sigmoidf_(s);
      p2out[(size_t)b*NC2+c] = p;
      w2out[(size_t)b*NC2+c] = p * gsc2[(size_t)b*NC2+c];
    }
  }
}

extern "C" void kernel_launch(void* const* d_in, const int* in_sizes, int n_in,
                              void* d_out, int out_size, void* d_ws, size_t ws_size,
                              hipStream_t stream) {
  const float* feat5   = (const float*)d_in[0];
  const float* feat8   = (const float*)d_in[1];
  const float* featcat = (const float*)d_in[2];
  const float* W0 = (const float*)d_in[3];
  const float* b0 = (const float*)d_in[4];
  const float* W1 = (const float*)d_in[5];
  const float* b1 = (const float*)d_in[6];
  const float* W2 = (const float*)d_in[7];
  const float* b2 = (const float*)d_in[8];
  const float* E0 = (const float*)d_in[9];
  const float* E1 = (const float*)d_in[10];
  const float* E2 = (const float*)d_in[11];
  const int*   g0 = (const int*)d_in[12];
  const int*   g1 = (const int*)d_in[13];

  float* out = (float*)d_out;
  float* ws  = (float*)d_ws;

  // ws layout (floats)
  size_t off = 0;
  float* P    = ws + off; off += 20ull*BB*HH;       // 655360 split-k partials
  float* hbuf = ws + off; off += 3ull*BB*HH;        // h0,h1,h2
  int*   cands1_i = (int*)(ws + off); off += (size_t)BB*NC1;
  float* gsc1 = ws + off; off += (size_t)BB*NC1;
  int*   cands2_i = (int*)(ws + off); off += (size_t)BB*NC2;
  float* gsc2 = ws + off; off += (size_t)BB*NC2;

  float* o_p0 = out;                       // 64*8192
  float* o_p1 = o_p0 + (size_t)BB*NG0;     // 64*256
  float* o_p2 = o_p1 + (size_t)BB*NC1;     // 64*704
  float* o_w1 = o_p2 + (size_t)BB*NC2;
  float* o_w2 = o_w1 + (size_t)BB*NC1;
  float* o_c1 = o_w2 + (size_t)BB*NC2;
  float* o_c2 = o_c1 + (size_t)BB*NC1;

  gemm_h_kernel<<<dim3(160), dim3(256), 0, stream>>>(feat5, feat8, featcat, W0, W1, W2, P);
  reduce_gelu_kernel<<<dim3(384), dim3(256), 0, stream>>>(P, b0, b1, b2, hbuf);
  level0_kernel<<<dim3(256), dim3(256), 0, stream>>>(hbuf, E0, o_p0);
  topk1_kernel<<<dim3(64), dim3(256), 0, stream>>>(o_p0, g0, cands1_i, gsc1, o_c1);
  level1_kernel<<<dim3(64,16), dim3(256), 0, stream>>>(hbuf + (size_t)BB*HH, cands1_i, gsc1, E1, o_p1, o_w1);
  topk2_kernel<<<dim3(64), dim3(256), 0, stream>>>(o_p1, cands1_i, g1, cands2_i, gsc2, o_c2);
  level2_kernel<<<dim3(64,44), dim3(256), 0, stream>>>(hbuf + 2ull*BB*HH, cands2_i, gsc2, E2, o_p2, o_w2);
}

// Round 2
// 99.844 us; speedup vs baseline: 1.3344x; 1.3344x over previous
//
#include <hip/hip_runtime.h>
#include <math.h>

#define BB 64
#define D0 768
#define D2 2304
#define HH 512
#define BBHH (BB*HH)
#define NG0 8192
#define NC0 8
#define NCH1 11
#define TK1 32
#define TK2 64
#define NC1 (TK1*NC0)   /* 256 */
#define NC2 (TK2*NCH1)  /* 704 */
#define SP0 6   /* k-splits for h0 (768 = 6*128) */
#define SP1 6   /* k-splits for h1 */
#define SP2 18  /* k-splits for h2 (2304 = 18*128) */

__device__ __forceinline__ float sigmoidf_(float x){ return 1.0f/(1.0f+expf(-x)); }
__device__ __forceinline__ float geluf_(float x){ return 0.5f*x*(1.0f+erff(x*0.70710678118654752f)); }
__device__ __forceinline__ unsigned long long maxu64_(unsigned long long a, unsigned long long b){ return a>b?a:b; }

// Block-wide bitonic sort of 256 u64 keys, DESCENDING. One key per thread.
// sbuf: 256-entry u64 LDS scratch. Returns this thread's sorted key (pos=tid).
__device__ __forceinline__ unsigned long long bitonic256_desc(
    unsigned long long key, int tid, unsigned long long* sbuf)
{
  #pragma unroll
  for (int k = 2; k <= 256; k <<= 1) {
    #pragma unroll
    for (int j = k >> 1; j > 0; j >>= 1) {
      unsigned long long other;
      if (j >= 64) {
        __syncthreads();
        sbuf[tid] = key;
        __syncthreads();
        other = sbuf[tid ^ j];
      } else {
        other = __shfl_xor(key, j, 64);
      }
      bool keep_max = ((tid & j) == 0) == ((tid & k) == 0);
      key = keep_max ? (key > other ? key : other)
                     : (key < other ? key : other);
    }
  }
  return key;
}

// ---------------- Kernel 1: h partial GEMMs (split-k), 240 blocks -----------
// m0: feat5@W0 (6 splits x 8 jtiles)  blocks 0..47
// m1: feat8@W1 (6 x 8)                blocks 48..95
// m2: featcat@W2 (18 x 8)             blocks 96..239
__global__ __launch_bounds__(256) void gemm_h_kernel(
    const float* __restrict__ feat5, const float* __restrict__ feat8,
    const float* __restrict__ featcat,
    const float* __restrict__ W0, const float* __restrict__ W1,
    const float* __restrict__ W2, float* __restrict__ P)
{
  int bid = blockIdx.x;
  const float* X; const float* W; int Dm, split, tile; float* Pb;
  if (bid < 48)      { X=feat5;   W=W0; Dm=D0; split=bid%6;  tile=bid/6;
                       Pb=P + (size_t)split*BBHH; }
  else if (bid < 96) { int l=bid-48; X=feat8; W=W1; Dm=D0; split=l%6; tile=l/6;
                       Pb=P + (size_t)(SP0+split)*BBHH; }
  else               { int l=bid-96; X=featcat; W=W2; Dm=D2; split=l%18; tile=l/18;
                       Pb=P + (size_t)(SP0+SP1+split)*BBHH; }
  int k0 = split*128;
  int jt = tile*64;
  __shared__ __align__(16) float At[32][68];   // [k][b]
  __shared__ __align__(16) float Bt[32][68];   // [k][j]
  int tid = threadIdx.x;
  int ti = tid >> 4, tj = tid & 15;
  float acc[4][4] = {};
  for (int ks = 0; ks < 128; ks += 32) {
    #pragma unroll
    for (int it = 0; it < 2; ++it) {             // A: 64b x 32k
      int q = tid + it*256;
      int b = q & 63, kq = q >> 6;
      float4 v = *(const float4*)(X + (size_t)b*Dm + k0 + ks + kq*4);
      At[kq*4+0][b]=v.x; At[kq*4+1][b]=v.y; At[kq*4+2][b]=v.z; At[kq*4+3][b]=v.w;
    }
    #pragma unroll
    for (int it = 0; it < 2; ++it) {             // B: 32k x 64j
      int q = tid + it*256;
      int j4 = q & 15, kk = q >> 4;
      float4 v = *(const float4*)(W + (size_t)(k0+ks+kk)*HH + jt + j4*4);
      *(float4*)&Bt[kk][j4*4] = v;
    }
    __syncthreads();
    #pragma unroll
    for (int k = 0; k < 32; ++k) {
      float4 a = *(const float4*)&At[k][ti*4];
      float4 b = *(const float4*)&Bt[k][tj*4];
      float av[4] = {a.x,a.y,a.z,a.w};
      float bv[4] = {b.x,b.y,b.z,b.w};
      #pragma unroll
      for (int r=0;r<4;++r)
        #pragma unroll
        for (int c=0;c<4;++c) acc[r][c] += av[r]*bv[c];
    }
    __syncthreads();
  }
  #pragma unroll
  for (int r=0;r<4;++r)
    #pragma unroll
    for (int c=0;c<4;++c) {
      int b = ti*4+r; int j = jt + tj*4 + c;
      Pb[(size_t)b*HH + j] = acc[r][c];
    }
}

// ---------------- Kernel 2: level0 p0 = sigmoid(gelu(P0)+bias @ E0^T) -------
// Fuses h0 split-reduction + bias + GELU into the A-tile staging.
// 256 blocks: btile = bid&1 (32 rows), gt = bid>>1 (64 g cols)
__global__ __launch_bounds__(256) void level0_kernel(
    const float* __restrict__ P, const float* __restrict__ b0v,
    const float* __restrict__ E0, float* __restrict__ p0out)
{
  int bid = blockIdx.x;
  int btile = bid & 1;
  int gt = bid >> 1;
  __shared__ __align__(16) float At[32][36];   // [k][b]
  __shared__ __align__(16) float Bt[32][68];   // [k][g]
  int tid = threadIdx.x;
  int ti = tid >> 4, tj = tid & 15;
  float acc[2][4] = {};
  for (int ks = 0; ks < HH; ks += 32) {
    {
      int bb = tid & 31, kq = tid >> 5;        // kq 0..7
      float4 a = make_float4(0.f,0.f,0.f,0.f);
      #pragma unroll
      for (int s=0;s<SP0;++s){
        const float4 p = *(const float4*)(P + (size_t)s*BBHH
                           + (size_t)(btile*32+bb)*HH + ks + kq*4);
        a.x+=p.x; a.y+=p.y; a.z+=p.z; a.w+=p.w;
      }
      float4 bv = *(const float4*)(b0v + ks + kq*4);
      At[kq*4+0][bb]=geluf_(a.x+bv.x);
      At[kq*4+1][bb]=geluf_(a.y+bv.y);
      At[kq*4+2][bb]=geluf_(a.z+bv.z);
      At[kq*4+3][bb]=geluf_(a.w+bv.w);
    }
    #pragma unroll
    for (int it=0; it<2; ++it) {
      int q = tid + it*256; int g = q & 63, kq = q >> 6;
      float4 v = *(const float4*)(E0 + (size_t)(gt*64+g)*HH + ks + kq*4);
      Bt[kq*4+0][g]=v.x; Bt[kq*4+1][g]=v.y; Bt[kq*4+2][g]=v.z; Bt[kq*4+3][g]=v.w;
    }
    __syncthreads();
    #pragma unroll
    for (int k=0;k<32;++k) {
      float2 a = *(const float2*)&At[k][ti*2];
      float4 b = *(const float4*)&Bt[k][tj*4];
      float av[2] = {a.x,a.y};
      float bv[4] = {b.x,b.y,b.z,b.w};
      #pragma unroll
      for (int r=0;r<2;++r)
        #pragma unroll
        for (int c=0;c<4;++c) acc[r][c] += av[r]*bv[c];
    }
    __syncthreads();
  }
  #pragma unroll
  for (int r=0;r<2;++r)
    #pragma unroll
    for (int c=0;c<4;++c) {
      int b = btile*32 + ti*2 + r;
      int g = gt*64 + tj*4 + c;
      p0out[(size_t)b*NG0 + g] = sigmoidf_(acc[r][c]);
    }
}

// ---------------- Kernel 3: top-32 via sort+threshold; also computes h1 -----
__global__ __launch_bounds__(256) void topk1_kernel(
    const float* __restrict__ p0, const int* __restrict__ g0,
    const float* __restrict__ P, const float* __restrict__ b1v,
    float* __restrict__ h1out,
    int* __restrict__ cands1_i, float* __restrict__ gsc1, float* __restrict__ out_c1)
{
  int b = blockIdx.x, tid = threadIdx.x;
  // h1 row b: reduce 6 split slices + bias + gelu (independent of topk)
  {
    int j = tid*2;
    float ax=0.f, ay=0.f;
    #pragma unroll
    for (int s=0;s<SP1;++s){
      float2 v = *(const float2*)(P + (size_t)(SP0+s)*BBHH + (size_t)b*HH + j);
      ax += v.x; ay += v.y;
    }
    float2 bv = *(const float2*)(b1v + j);
    h1out[(size_t)b*HH + j]   = geluf_(ax + bv.x);
    h1out[(size_t)b*HH + j+1] = geluf_(ay + bv.y);
  }
  // phase 1: per-thread max over its contiguous 32 elements
  const float* row = p0 + (size_t)b*NG0;
  const float4* rp = (const float4*)(row + tid*32);
  unsigned long long m = 0ull;
  #pragma unroll
  for (int t=0;t<8;++t){
    float4 v = rp[t];
    unsigned i0 = (unsigned)(tid*32 + t*4);
    m = maxu64_(m, ((unsigned long long)__float_as_uint(v.x)<<32) | (unsigned long long)(0xFFFFFFFFu-(i0+0)));
    m = maxu64_(m, ((unsigned long long)__float_as_uint(v.y)<<32) | (unsigned long long)(0xFFFFFFFFu-(i0+1)));
    m = maxu64_(m, ((unsigned long long)__float_as_uint(v.z)<<32) | (unsigned long long)(0xFFFFFFFFu-(i0+2)));
    m = maxu64_(m, ((unsigned long long)__float_as_uint(v.w)<<32) | (unsigned long long)(0xFFFFFFFFu-(i0+3)));
  }
  __shared__ unsigned long long sbuf[256];
  __shared__ unsigned long long slist[256];
  __shared__ int scnt;
  __shared__ float s_sc[TK1];
  __shared__ int   s_idx[TK1];
  if (tid==0) scnt = 0;
  __syncthreads();
  // sort the 256 per-thread maxima; t32 = 32nd largest maximum.
  // Exactness: >=32 distinct elements have key >= t32, so global top-32 all
  // satisfy key >= t32 -> filter is a superset.
  unsigned long long sk = bitonic256_desc(m, tid, sbuf);
  __syncthreads();
  sbuf[tid] = sk;
  __syncthreads();
  unsigned long long t32 = sbuf[31];
  __syncthreads();
  // compact all elements with key >= t32 (expected ~34)
  #pragma unroll
  for (int t=0;t<8;++t){
    float4 v = rp[t];
    unsigned i0 = (unsigned)(tid*32 + t*4);
    unsigned long long k0 = ((unsigned long long)__float_as_uint(v.x)<<32) | (unsigned long long)(0xFFFFFFFFu-(i0+0));
    unsigned long long k1 = ((unsigned long long)__float_as_uint(v.y)<<32) | (unsigned long long)(0xFFFFFFFFu-(i0+1));
    unsigned long long k2 = ((unsigned long long)__float_as_uint(v.z)<<32) | (unsigned long long)(0xFFFFFFFFu-(i0+2));
    unsigned long long k3 = ((unsigned long long)__float_as_uint(v.w)<<32) | (unsigned long long)(0xFFFFFFFFu-(i0+3));
    if (k0 >= t32) { int p = atomicAdd(&scnt,1); if (p<256) slist[p]=k0; }
    if (k1 >= t32) { int p = atomicAdd(&scnt,1); if (p<256) slist[p]=k1; }
    if (k2 >= t32) { int p = atomicAdd(&scnt,1); if (p<256) slist[p]=k2; }
    if (k3 >= t32) { int p = atomicAdd(&scnt,1); if (p<256) slist[p]=k3; }
  }
  __syncthreads();
  int cnt = scnt;
  unsigned long long key2 = (tid < cnt) ? slist[tid] : 0ull;
  key2 = bitonic256_desc(key2, tid, sbuf);
  __syncthreads();
  sbuf[tid] = key2;
  __syncthreads();
  if (tid < TK1) {
    unsigned long long w = sbuf[tid];
    s_idx[tid] = (int)(0xFFFFFFFFu - (unsigned)(w & 0xFFFFFFFFull));
    s_sc[tid]  = __uint_as_float((unsigned)(w>>32));
  }
  __syncthreads();
  if (tid < NC1) {
    int k = tid >> 3, c = tid & 7;
    int cand = g0[(size_t)s_idx[k]*NC0 + c];
    cands1_i[(size_t)b*NC1+tid] = cand;
    gsc1[(size_t)b*NC1+tid] = s_sc[k];
    out_c1[(size_t)b*NC1+tid] = (float)cand;
  }
}

// ---------------- Kernel 4: level1 gather-GEMV over E1 ----------------------
__global__ __launch_bounds__(256) void level1_kernel(
    const float* __restrict__ h1, const int* __restrict__ cands1_i,
    const float* __restrict__ gsc1, const float* __restrict__ E1,
    float* __restrict__ p1out, float* __restrict__ w1out)
{
  int b = blockIdx.x; int tid = threadIdx.x;
  int lane = tid & 63, wid = tid >> 6;
  const float4* h4 = (const float4*)(h1 + (size_t)b*HH);
  float4 ha = h4[lane*2], hb = h4[lane*2+1];
  int cbase = blockIdx.y*16 + wid*4;
  const int* ci = cands1_i + (size_t)b*NC1 + cbase;
  int id0=ci[0], id1=ci[1], id2=ci[2], id3=ci[3];
  const float4* e0 = (const float4*)(E1 + (size_t)id0*HH);
  const float4* e1 = (const float4*)(E1 + (size_t)id1*HH);
  const float4* e2 = (const float4*)(E1 + (size_t)id2*HH);
  const float4* e3 = (const float4*)(E1 + (size_t)id3*HH);
  float4 a0=e0[lane*2], c0=e0[lane*2+1];
  float4 a1=e1[lane*2], c1=e1[lane*2+1];
  float4 a2=e2[lane*2], c2=e2[lane*2+1];
  float4 a3=e3[lane*2], c3=e3[lane*2+1];
  float s0 = ha.x*a0.x+ha.y*a0.y+ha.z*a0.z+ha.w*a0.w + hb.x*c0.x+hb.y*c0.y+hb.z*c0.z+hb.w*c0.w;
  float s1 = ha.x*a1.x+ha.y*a1.y+ha.z*a1.z+ha.w*a1.w + hb.x*c1.x+hb.y*c1.y+hb.z*c1.z+hb.w*c1.w;
  float s2 = ha.x*a2.x+ha.y*a2.y+ha.z*a2.z+ha.w*a2.w + hb.x*c2.x+hb.y*c2.y+hb.z*c2.z+hb.w*c2.w;
  float s3 = ha.x*a3.x+ha.y*a3.y+ha.z*a3.z+ha.w*a3.w + hb.x*c3.x+hb.y*c3.y+hb.z*c3.z+hb.w*c3.w;
  #pragma unroll
  for (int off=1; off<64; off<<=1) {
    s0 += __shfl_xor(s0, off);
    s1 += __shfl_xor(s1, off);
    s2 += __shfl_xor(s2, off);
    s3 += __shfl_xor(s3, off);
  }
  if (lane==0) {
    const float* gs = gsc1 + (size_t)b*NC1 + cbase;
    float p;
    p = sigmoidf_(s0); p1out[(size_t)b*NC1+cbase+0]=p; w1out[(size_t)b*NC1+cbase+0]=p*gs[0];
    p = sigmoidf_(s1); p1out[(size_t)b*NC1+cbase+1]=p; w1out[(size_t)b*NC1+cbase+1]=p*gs[1];
    p = sigmoidf_(s2); p1out[(size_t)b*NC1+cbase+2]=p; w1out[(size_t)b*NC1+cbase+2]=p*gs[2];
    p = sigmoidf_(s3); p1out[(size_t)b*NC1+cbase+3]=p; w1out[(size_t)b*NC1+cbase+3]=p*gs[3];
  }
}

// ---------------- Kernel 5: top-64 of 256 via full bitonic; also h2 ---------
__global__ __launch_bounds__(256) void topk2_kernel(
    const float* __restrict__ p1, const int* __restrict__ cands1_i,
    const int* __restrict__ g1,
    const float* __restrict__ P, const float* __restrict__ b2v,
    float* __restrict__ h2out,
    int* __restrict__ cands2_i, float* __restrict__ gsc2, float* __restrict__ out_c2)
{
  int b = blockIdx.x, tid = threadIdx.x;
  // h2 row b: reduce 18 split slices + bias + gelu
  {
    int j = tid*2;
    float ax=0.f, ay=0.f;
    #pragma unroll
    for (int s=0;s<SP2;++s){
      float2 v = *(const float2*)(P + (size_t)(SP0+SP1+s)*BBHH + (size_t)b*HH + j);
      ax += v.x; ay += v.y;
    }
    float2 bv = *(const float2*)(b2v + j);
    h2out[(size_t)b*HH + j]   = geluf_(ax + bv.x);
    h2out[(size_t)b*HH + j+1] = geluf_(ay + bv.y);
  }
  float v = p1[(size_t)b*NC1 + tid];
  unsigned long long key = ((unsigned long long)__float_as_uint(v)<<32) |
                           (unsigned long long)(0xFFFFFFFFu - (unsigned)tid);
  __shared__ unsigned long long sbuf[256];
  __shared__ float s_sc[TK2];
  __shared__ int   s_idx[TK2];
  key = bitonic256_desc(key, tid, sbuf);
  __syncthreads();
  sbuf[tid] = key;
  __syncthreads();
  if (tid < TK2) {
    unsigned long long w = sbuf[tid];
    s_idx[tid] = (int)(0xFFFFFFFFu - (unsigned)(w & 0xFFFFFFFFull));
    s_sc[tid]  = __uint_as_float((unsigned)(w>>32));
  }
  __syncthreads();
  for (int e=tid; e<NC2; e+=256) {
    int k = e/NCH1, c = e - k*NCH1;
    int meta = cands1_i[(size_t)b*NC1 + s_idx[k]];
    int cand = g1[(size_t)meta*NCH1 + c];
    cands2_i[(size_t)b*NC2+e] = cand;
    gsc2[(size_t)b*NC2+e] = s_sc[k];
    out_c2[(size_t)b*NC2+e] = (float)cand;
  }
}

// ---------------- Kernel 6: level2 gather-GEMV over E2 ----------------------
__global__ __launch_bounds__(256) void level2_kernel(
    const float* __restrict__ h2, const int* __restrict__ cands2_i,
    const float* __restrict__ gsc2, const float* __restrict__ E2,
    float* __restrict__ p2out, float* __restrict__ w2out)
{
  int b = blockIdx.x; int tid = threadIdx.x;
  int lane = tid & 63, wid = tid >> 6;
  const float4* h4 = (const float4*)(h2 + (size_t)b*HH);
  float4 ha = h4[lane*2], hb = h4[lane*2+1];
  int cbase = blockIdx.y*16 + wid*4;
  const int* ci = cands2_i + (size_t)b*NC2 + cbase;
  int id0=ci[0], id1=ci[1], id2=ci[2], id3=ci[3];
  const float4* e0 = (const float4*)(E2 + (size_t)id0*HH);
  const float4* e1 = (const float4*)(E2 + (size_t)id1*HH);
  const float4* e2 = (const float4*)(E2 + (size_t)id2*HH);
  const float4* e3 = (const float4*)(E2 + (size_t)id3*HH);
  float4 a0=e0[lane*2], c0=e0[lane*2+1];
  float4 a1=e1[lane*2], c1=e1[lane*2+1];
  float4 a2=e2[lane*2], c2=e2[lane*2+1];
  float4 a3=e3[lane*2], c3=e3[lane*2+1];
  float s0 = ha.x*a0.x+ha.y*a0.y+ha.z*a0.z+ha.w*a0.w + hb.x*c0.x+hb.y*c0.y+hb.z*c0.z+hb.w*c0.w;
  float s1 = ha.x*a1.x+ha.y*a1.y+ha.z*a1.z+ha.w*a1.w + hb.x*c1.x+hb.y*c1.y+hb.z*c1.z+hb.w*c1.w;
  float s2 = ha.x*a2.x+ha.y*a2.y+ha.z*a2.z+ha.w*a2.w + hb.x*c2.x+hb.y*c2.y+hb.z*c2.z+hb.w*c2.w;
  float s3 = ha.x*a3.x+ha.y*a3.y+ha.z*a3.z+ha.w*a3.w + hb.x*c3.x+hb.y*c3.y+hb.z*c3.z+hb.w*c3.w;
  #pragma unroll
  for (int off=1; off<64; off<<=1) {
    s0 += __shfl_xor(s0, off);
    s1 += __shfl_xor(s1, off);
    s2 += __shfl_xor(s2, off);
    s3 += __shfl_xor(s3, off);
  }
  if (lane==0) {
    const float* gs = gsc2 + (size_t)b*NC2 + cbase;
    float p;
    p = (s0==0.0f)?0.0f:sigmoidf_(s0); p2out[(size_t)b*NC2+cbase+0]=p; w2out[(size_t)b*NC2+cbase+0]=p*gs[0];
    p = (s1==0.0f)?0.0f:sigmoidf_(s1); p2out[(size_t)b*NC2+cbase+1]=p; w2out[(size_t)b*NC2+cbase+1]=p*gs[1];
    p = (s2==0.0f)?0.0f:sigmoidf_(s2); p2out[(size_t)b*NC2+cbase+2]=p; w2out[(size_t)b*NC2+cbase+2]=p*gs[2];
    p = (s3==0.0f)?0.0f:sigmoidf_(s3); p2out[(size_t)b*NC2+cbase+3]=p; w2out[(size_t)b*NC2+cbase+3]=p*gs[3];
  }
}

extern "C" void kernel_launch(void* const* d_in, const int* in_sizes, int n_in,
                              void* d_out, int out_size, void* d_ws, size_t ws_size,
                              hipStream_t stream) {
  const float* feat5   = (const float*)d_in[0];
  const float* feat8   = (const float*)d_in[1];
  const float* featcat = (const float*)d_in[2];
  const float* W0 = (const float*)d_in[3];
  const float* b0 = (const float*)d_in[4];
  const float* W1 = (const float*)d_in[5];
  const float* b1 = (const float*)d_in[6];
  const float* W2 = (const float*)d_in[7];
  const float* b2 = (const float*)d_in[8];
  const float* E0 = (const float*)d_in[9];
  const float* E1 = (const float*)d_in[10];
  const float* E2 = (const float*)d_in[11];
  const int*   g0 = (const int*)d_in[12];
  const int*   g1 = (const int*)d_in[13];

  float* out = (float*)d_out;
  float* ws  = (float*)d_ws;

  // ws layout (floats)
  size_t off = 0;
  float* P    = ws + off; off += (size_t)(SP0+SP1+SP2)*BBHH;  // 30 split slices
  float* hbuf = ws + off; off += 2ull*BBHH;                   // h1, h2
  int*   cands1_i = (int*)(ws + off); off += (size_t)BB*NC1;
  float* gsc1 = ws + off; off += (size_t)BB*NC1;
  int*   cands2_i = (int*)(ws + off); off += (size_t)BB*NC2;
  float* gsc2 = ws + off; off += (size_t)BB*NC2;

  float* h1 = hbuf;
  float* h2 = hbuf + BBHH;

  float* o_p0 = out;                       // 64*8192
  float* o_p1 = o_p0 + (size_t)BB*NG0;     // 64*256
  float* o_p2 = o_p1 + (size_t)BB*NC1;     // 64*704
  float* o_w1 = o_p2 + (size_t)BB*NC2;
  float* o_w2 = o_w1 + (size_t)BB*NC1;
  float* o_c1 = o_w2 + (size_t)BB*NC2;
  float* o_c2 = o_c1 + (size_t)BB*NC1;

  gemm_h_kernel<<<dim3(240), dim3(256), 0, stream>>>(feat5, feat8, featcat, W0, W1, W2, P);
  level0_kernel<<<dim3(256), dim3(256), 0, stream>>>(P, b0, E0, o_p0);
  topk1_kernel<<<dim3(64), dim3(256), 0, stream>>>(o_p0, g0, P, b1, h1, cands1_i, gsc1, o_c1);
  level1_kernel<<<dim3(64,16), dim3(256), 0, stream>>>(h1, cands1_i, gsc1, E1, o_p1, o_w1);
  topk2_kernel<<<dim3(64), dim3(256), 0, stream>>>(o_p1, cands1_i, g1, P, b2, h2, cands2_i, gsc2, o_c2);
  level2_kernel<<<dim3(64,44), dim3(256), 0, stream>>>(h2, cands2_i, gsc2, E2, o_p2, o_w2);
}